// Round 16
// baseline (146.575 us; speedup 1.0000x reference)
//
#include <hip/hip_runtime.h>
#include <hip/hip_bf16.h>
#include <stdint.h>

#define DEVI __device__ __forceinline__

typedef __attribute__((ext_vector_type(8))) short short8;
typedef __attribute__((ext_vector_type(4))) short short4v;
typedef __attribute__((ext_vector_type(4))) float floatx4;

DEVI ushort f2bf(float f) {
  union { float f; uint32_t u; } v; v.f = f;
  uint32_t u = v.u;
  uint32_t r = (u + 0x7FFFu + ((u >> 16) & 1u)) >> 16;
  return (ushort)r;
}
DEVI ushort f2bf_fast(float f) {
  union { float f; uint32_t u; } v; v.f = f;
  return (ushort)((v.u + 0x8000u) >> 16);
}
DEVI float bf2f(ushort h) {
  union { uint32_t u; float f; } v; v.u = ((uint32_t)h) << 16;
  return v.f;
}
DEVI void gld_lds16(const void* g, void* l) {
  __builtin_amdgcn_global_load_lds(
      (const __attribute__((address_space(1))) unsigned int*)g,
      (__attribute__((address_space(3))) unsigned int*)l, 16, 0, 0);
}

// ------- fused cast fp32 -> bf16 (x, qkv_w, proj_w) + RoPE table -------
__global__ __launch_bounds__(256, 4) void cast_all(
    const float* __restrict__ x, const float* __restrict__ w1,
    const float* __restrict__ w2, ushort* __restrict__ xb,
    ushort* __restrict__ w1b, ushort* __restrict__ w2b,
    float2* __restrict__ tab) {
  const int N1 = 4096 * 1024, N2 = 3072 * 1024, N3 = 1024 * 1024;
  int id = blockIdx.x * 256 + threadIdx.x;
  if (id < 32768) {  // RoPE cos/sin table: 1024 positions x 32 freq pairs
    int j = id & 31, n = id >> 5;
    float inv = powf(10000.0f, -(float)(2 * j) / 64.0f);
    float fr = (float)n * inv;
    tab[id] = make_float2(cosf(fr), sinf(fr));
  }
  int i = id * 4;
  const int total = N1 + N2 + N3;
  int stride = gridDim.x * 256 * 4;
  for (; i < total; i += stride) {
    const float* src; ushort* dst; int off;
    if (i < N1) { src = x; dst = xb; off = i; }
    else if (i < N1 + N2) { src = w1; dst = w1b; off = i - N1; }
    else { src = w2; dst = w2b; off = i - N1 - N2; }
    float4 v = *(const float4*)(src + off);
    ushort4 o;
    o.x = f2bf(v.x); o.y = f2bf(v.y); o.z = f2bf(v.z); o.w = f2bf(v.w);
    *(ushort4*)(dst + off) = o;
  }
}

// ---------------- GEMM1: qkv = x @ W^T + b, fused RoPE + scatter ----------
// r15 K-loop (2-phase dbuf, BK=32, 128^2, conflict-free swizzle, XCD swizzle,
// grid 768). Epilogues all LDS-packed for coalesced wide stores:
//   role 2 (V): transpose via T stride-264 -> Vt (b,h,d,n)    [r15-proven]
//   role 0/1 (Q/K): RoPE in regs, pack via T stride-272 -> 128B/thread runs
__global__ __launch_bounds__(256, 4) void gemm_qkv(
    const ushort* __restrict__ A, const ushort* __restrict__ Bm,
    const float* __restrict__ bias, const float2* __restrict__ tab,
    ushort* __restrict__ Qb, ushort* __restrict__ Kb,
    ushort* __restrict__ Vt) {
  __shared__ __align__(16) char pool[34816];  // K-loop 32KB; epi T <= 34816
  char* AsP = pool;            // [2][8192]: 128 rows x 64 B per buf
  char* BsP = pool + 16384;    // [2][8192]
  const int tid = threadIdx.x;
  const int w = tid >> 6, lane = tid & 63;

  // XCD swizzle: grid 768 = 32 mt x 24 nt, XCD region 8mt x 12nt
  const int bid = blockIdx.x;
  const int xcd = bid & 7, i5 = bid >> 3;       // i5 in [0,96)
  const int lm = i5 & 7, ln = i5 >> 3;          // 8 x 12
  const int mt = (xcd & 3) * 8 + lm;            // [0,32)
  const int nt = (xcd >> 2) * 12 + ln;          // [0,24)
  const int m0 = mt * 128, n0 = nt * 128;

  const int wm = (w >> 1) * 64, wn = (w & 1) * 64;
  const int lrow = lane & 15, g = lane >> 4;
  const int swrd = (g ^ ((lrow >> 1) & 3)) << 4;  // read-side swizzled chunk

  // staging source pre-swizzled: chunk' = (lane&3) ^ ((lane>>3)&3)
  const int swsrc = (((lane & 3) ^ ((lane >> 3) & 3)) << 4);
  const char* aG = (const char*)A + (size_t)(m0 + w * 32 + (lane >> 2)) * 2048 + swsrc;
  const char* bG = (const char*)Bm + (size_t)(n0 + w * 32 + (lane >> 2)) * 2048 + swsrc;
  const int ldst = w * 2048 + lane * 16;

  auto STAGE = [&](const int buf) {
    gld_lds16(aG, AsP + buf * 8192 + ldst);
    gld_lds16(aG + 16 * 2048, AsP + buf * 8192 + ldst + 1024);
    gld_lds16(bG, BsP + buf * 8192 + ldst);
    gld_lds16(bG + 16 * 2048, BsP + buf * 8192 + ldst + 1024);
    aG += 64; bG += 64;  // advance K by 32 elements
  };

  floatx4 acc[4][4] = {};

  auto TILE = [&](const int buf) {
    short8 af[4], bf[4];
#pragma unroll
    for (int t = 0; t < 4; ++t) {
      af[t] = *(const short8*)(AsP + buf * 8192 + (wm + t * 16 + lrow) * 64 + swrd);
      bf[t] = *(const short8*)(BsP + buf * 8192 + (wn + t * 16 + lrow) * 64 + swrd);
    }
#pragma unroll
    for (int i = 0; i < 4; ++i)
#pragma unroll
      for (int j = 0; j < 4; ++j)
        acc[i][j] = __builtin_amdgcn_mfma_f32_16x16x32_bf16(af[i], bf[j], acc[i][j], 0, 0, 0);
  };

  STAGE(0);
  asm volatile("s_waitcnt vmcnt(0)" ::: "memory");
  __builtin_amdgcn_s_barrier();
  __builtin_amdgcn_sched_barrier(0);

  for (int t = 0; t < 32; t += 2) {
    STAGE(1);
    __builtin_amdgcn_sched_barrier(0);
    TILE(0);
    asm volatile("s_waitcnt vmcnt(0)" ::: "memory");
    __builtin_amdgcn_s_barrier();
    __builtin_amdgcn_sched_barrier(0);

    if (t + 2 < 32) STAGE(0);
    __builtin_amdgcn_sched_barrier(0);
    TILE(1);
    asm volatile("s_waitcnt vmcnt(0)" ::: "memory");
    __builtin_amdgcn_s_barrier();
    __builtin_amdgcn_sched_barrier(0);
  }

  const int role = n0 >> 10;  // 0=q, 1=k, 2=v (block cols never straddle)
  const int b = m0 >> 10, nbase = m0 & 1023;
  if (role == 2) {
    // ---- V path (r15-proven): LDS transpose -> direct Vt (b,h,d,n) ----
    char* T = pool;
#pragma unroll
    for (int i = 0; i < 4; ++i) {
      int lr0 = wm + i * 16 + g * 4;  // 4 consecutive local rows
#pragma unroll
      for (int j = 0; j < 4; ++j) {
        int lc = wn + j * 16 + lrow;
        float bv = bias[n0 + lc];
        ushort4 o;
#pragma unroll
        for (int r = 0; r < 4; ++r) ((ushort*)&o)[r] = f2bf(acc[i][j][r] + bv);
        *(ushort4*)(T + lc * 264 + lr0 * 2) = o;
      }
    }
    __syncthreads();
    const int h0 = (n0 - 2048) >> 6;
    const int c = tid >> 1, half = tid & 1;   // col 0..127, n-half 0..1
    const int h = h0 + (c >> 6), d = c & 63;
    ushort* dst = Vt + (size_t)(b * 16 + h) * 65536 + (size_t)d * 1024 + nbase + half * 64;
    const char* src = T + c * 264 + half * 128;
#pragma unroll
    for (int k = 0; k < 16; ++k)
      *(short4v*)(dst + k * 4) = *(const short4v*)(src + k * 8);
  } else {
    // ---- Q/K path: RoPE in regs, pack T[n_loc][c_loc] (272B rows), then
    // each thread stores one contiguous 128B run of (b,h,n,d) output ----
    const float sc = (1.0f / 64.0f) * 1.44269504088896f;  // scale^2 * log2(e)
    char* T = pool;
#pragma unroll
    for (int i = 0; i < 4; ++i) {
      int lr0 = wm + i * 16 + g * 4;
#pragma unroll
      for (int j = 0; j < 4; ++j) {
        int lc = wn + j * 16 + lrow;
        int ncol = n0 + lc;
        float bv = bias[ncol];
        int d = ncol & 63;
#pragma unroll
        for (int r = 0; r < 4; ++r) {
          float v = acc[i][j][r] + bv;
          int n = (nbase + lr0 + r);  // position within batch (m0 same b)
          float p = __shfl_xor(v, 1);  // partner col (d^1), same row
          float2 cs = tab[n * 32 + (d >> 1)];
          float o = (d & 1) ? (v * cs.x + p * cs.y) : (v * cs.x - p * cs.y);
          if (role == 0) o *= sc;
          *(ushort*)(T + (lr0 + r) * 272 + lc * 2) = f2bf(o);
        }
      }
    }
    __syncthreads();
    const int h0 = (n0 & 1023) >> 6;
    const int n_l = tid >> 1, half = tid & 1;  // local row, h-half
    ushort* dst = (role == 0 ? Qb : Kb) +
                  (size_t)(b * 16 + h0 + half) * 65536 + (size_t)(nbase + n_l) * 64;
    const char* src = T + n_l * 272 + half * 128;
#pragma unroll
    for (int k = 0; k < 8; ++k)
      *(short8*)(dst + k * 8) = *(const short8*)(src + k * 16);
  }
}

// ---------------- GEMM2: out = AO @ proj_w^T + b (fp32 out) ----------------
// r12 3-stage counted pipeline + swizzled conflict-free reads. Grid 256.
__global__ __launch_bounds__(256, 3) void gemm_proj(
    const ushort* __restrict__ A, const ushort* __restrict__ Bm,
    const float* __restrict__ bias, float* __restrict__ Cout) {
  __shared__ __align__(16) char lds[3][16384];
  char* L0 = &lds[0][0];
  const int tid = threadIdx.x;
  const int w = tid >> 6, lane = tid & 63;

  const int bid = blockIdx.x;
  const int xcd = bid & 7, i5 = bid >> 3;
  const int lm = i5 & 7, ln = i5 >> 3;
  const int mt = (xcd & 3) * 8 + lm;
  const int nt = (xcd >> 2) * 4 + ln;
  const int m0 = mt * 128, n0 = nt * 128;

  const int wm = (w >> 1) * 64, wn = (w & 1) * 64;
  const int lrow = lane & 15, g = lane >> 4;
  const int swrd = (g ^ ((lrow >> 1) & 3)) << 4;

  const int swsrc = (((lane & 3) ^ ((lane >> 3) & 3)) << 4);
  const char* aG = (const char*)A + (size_t)(m0 + w * 32 + (lane >> 2)) * 2048 + swsrc;
  const char* bG = (const char*)Bm + (size_t)(n0 + w * 32 + (lane >> 2)) * 2048 + swsrc;
  const int ldst = w * 2048 + lane * 16;

  auto STAGE = [&](const int base) {
    char* L = L0 + base;
    gld_lds16(aG, L + ldst);
    gld_lds16(aG + 16 * 2048, L + ldst + 1024);
    gld_lds16(bG, L + 8192 + ldst);
    gld_lds16(bG + 16 * 2048, L + 8192 + ldst + 1024);
    aG += 64; bG += 64;
  };

  floatx4 acc[4][4] = {};

  auto TILE = [&](const int base) {
    const char* L = L0 + base;
    short8 af[4], bf[4];
#pragma unroll
    for (int t = 0; t < 4; ++t) {
      af[t] = *(const short8*)(L + (wm + t * 16 + lrow) * 64 + swrd);
      bf[t] = *(const short8*)(L + 8192 + (wn + t * 16 + lrow) * 64 + swrd);
    }
#pragma unroll
    for (int i = 0; i < 4; ++i)
#pragma unroll
      for (int j = 0; j < 4; ++j)
        acc[i][j] = __builtin_amdgcn_mfma_f32_16x16x32_bf16(af[i], bf[j], acc[i][j], 0, 0, 0);
  };

  STAGE(0);
  STAGE(16384);
  int bT = 0, bS = 32768;

  for (int t = 0; t < 31; ++t) {
    asm volatile("s_waitcnt vmcnt(4)" ::: "memory");
    __builtin_amdgcn_s_barrier();
    __builtin_amdgcn_sched_barrier(0);
    if (t < 30) STAGE(bS);
    __builtin_amdgcn_sched_barrier(0);
    TILE(bT);
    __builtin_amdgcn_sched_barrier(0);
    bT += 16384; if (bT == 49152) bT = 0;
    bS += 16384; if (bS == 49152) bS = 0;
  }
  asm volatile("s_waitcnt vmcnt(0)" ::: "memory");
  __builtin_amdgcn_s_barrier();
  __builtin_amdgcn_sched_barrier(0);
  TILE(bT);

#pragma unroll
  for (int i = 0; i < 4; ++i) {
    int mrow = m0 + wm + i * 16 + (lane >> 4) * 4;
#pragma unroll
    for (int j = 0; j < 4; ++j) {
      int ncol = n0 + wn + j * 16 + (lane & 15);
      float bv = bias[ncol];
#pragma unroll
      for (int r = 0; r < 4; ++r)
        Cout[(size_t)(mrow + r) * 1024 + ncol] = acc[i][j][r] + bv;
    }
  }
}

// ---------------- Flash attention v6: 128 q-rows/block ----------------
// K-fragments loaded once serve both q-halves; V-fragments feed 2 MFMAs.
// Per-tile ds_reads and KV staging halve per unit work. Grid 512.
__global__ __launch_bounds__(256, 4) void attn(
    const ushort* __restrict__ Q, const ushort* __restrict__ Kc,
    const ushort* __restrict__ Vt, ushort* __restrict__ AO) {
  __shared__ char lds[2][16384];  // per buf: K tile 8KB @0, V tile 8KB @8192
  char* ldsbase = &lds[0][0];
  int id = blockIdx.x;
  int bh = id & 63, qi = id >> 6;   // grid 512: qi in [0,8)
  int b = bh >> 4, h = bh & 15;
  int q0 = qi * 128;
  int tid = threadIdx.x, w = tid >> 6, lane = tid & 63;
  int l15 = lane & 15, g = lane >> 4;
  const ushort* Qbh = Q + (size_t)bh * 65536;
  const char* Kbh = (const char*)(Kc + (size_t)bh * 65536);
  const char* Vbh = (const char*)(Vt + (size_t)bh * 65536);

  short8 qf[2][2];
#pragma unroll
  for (int hh = 0; hh < 2; ++hh)
#pragma unroll
    for (int ks = 0; ks < 2; ++ks)
      qf[hh][ks] = *(const short8*)(Qbh + (size_t)(q0 + hh * 64 + w * 16 + l15) * 64 + ks * 32 + g * 8);

  int kaddr[8];
#pragma unroll
  for (int ks = 0; ks < 2; ++ks)
#pragma unroll
    for (int nt = 0; nt < 4; ++nt) {
      int row = nt * 16 + l15;
      kaddr[ks * 4 + nt] = (row * 128 + ks * 64 + g * 16) ^ ((row & 7) << 4);
    }
  int vaddr[16];
#pragma unroll
  for (int ch = 0; ch < 2; ++ch)
#pragma unroll
    for (int dt = 0; dt < 4; ++dt)
#pragma unroll
      for (int hf = 0; hf < 2; ++hf) {
        int row = dt * 16 + l15;
        vaddr[(ch * 4 + dt) * 2 + hf] =
            8192 + ((row * 128 + ch * 64 + hf * 32 + g * 8) ^ ((row & 7) << 4));
      }

  const int d0 = w * 2048 + lane * 16;
  const int d1 = d0 + 1024;
  const int r0 = d0 >> 7, r1 = d1 >> 7;
  const int s0 = d0 ^ ((r0 & 7) << 4), s1 = d1 ^ ((r1 & 7) << 4);
  const char* pK0 = Kbh + s0;
  const char* pK1 = Kbh + s1;
  const char* pV0 = Vbh + r0 * 2048 + (s0 & 127);
  const char* pV1 = Vbh + r1 * 2048 + (s1 & 127);

  auto STAGE = [&](const int B) {
    gld_lds16(pK0, ldsbase + B + d0);
    gld_lds16(pK1, ldsbase + B + d1);
    gld_lds16(pV0, ldsbase + B + 8192 + d0);
    gld_lds16(pV1, ldsbase + B + 8192 + d1);
    pK0 += 8192; pK1 += 8192; pV0 += 128; pV1 += 128;
  };

  floatx4 oacc[2][4] = {};
  float lrun[2] = {0.f, 0.f};

  auto TILE = [&](const int B) {
    short8 kf[8];
#pragma unroll
    for (int t = 0; t < 8; ++t)
      kf[t] = *(const short8*)(ldsbase + B + kaddr[t]);

    short8 pa[2][2];
#pragma unroll
    for (int hh = 0; hh < 2; ++hh) {
      floatx4 sacc[4] = {};
      __builtin_amdgcn_s_setprio(1);
#pragma unroll
      for (int ks = 0; ks < 2; ++ks)
#pragma unroll
        for (int nt = 0; nt < 4; ++nt)
          sacc[nt] = __builtin_amdgcn_mfma_f32_16x16x32_bf16(kf[ks * 4 + nt], qf[hh][ks], sacc[nt], 0, 0, 0);
      __builtin_amdgcn_s_setprio(0);

      float rs = 0.f;
#pragma unroll
      for (int nt = 0; nt < 4; ++nt)
#pragma unroll
        for (int r = 0; r < 4; ++r) {
          float p = __builtin_amdgcn_exp2f(sacc[nt][r]);
          sacc[nt][r] = p;
          rs += p;
        }
      lrun[hh] += rs;
#pragma unroll
      for (int ch = 0; ch < 2; ++ch)
#pragma unroll
        for (int r = 0; r < 4; ++r) {
          pa[hh][ch][r] = (short)f2bf_fast(sacc[2 * ch][r]);
          pa[hh][ch][r + 4] = (short)f2bf_fast(sacc[2 * ch + 1][r]);
        }
    }

    __builtin_amdgcn_s_setprio(1);
#pragma unroll
    for (int ch = 0; ch < 2; ++ch)
#pragma unroll
      for (int dt = 0; dt < 4; ++dt) {
        short4v va = *(const short4v*)(ldsbase + B + vaddr[(ch * 4 + dt) * 2]);
        short4v vb = *(const short4v*)(ldsbase + B + vaddr[(ch * 4 + dt) * 2 + 1]);
        short8 vf = __builtin_shufflevector(va, vb, 0, 1, 2, 3, 4, 5, 6, 7);
#pragma unroll
        for (int hh = 0; hh < 2; ++hh)
          oacc[hh][dt] = __builtin_amdgcn_mfma_f32_16x16x32_bf16(pa[hh][ch], vf, oacc[hh][dt], 0, 0, 0);
      }
    __builtin_amdgcn_s_setprio(0);
  };

  STAGE(0);
  asm volatile("s_waitcnt vmcnt(0)" ::: "memory");
  __builtin_amdgcn_s_barrier();
  __builtin_amdgcn_sched_barrier(0);

  for (int kt = 0; kt < 16; kt += 2) {
    STAGE(16384);
    __builtin_amdgcn_sched_barrier(0);
    TILE(0);
    asm volatile("s_waitcnt vmcnt(0)" ::: "memory");
    __builtin_amdgcn_s_barrier();
    __builtin_amdgcn_sched_barrier(0);

    if (kt + 2 < 16) STAGE(0);
    __builtin_amdgcn_sched_barrier(0);
    TILE(16384);
    asm volatile("s_waitcnt vmcnt(0)" ::: "memory");
    __builtin_amdgcn_s_barrier();
    __builtin_amdgcn_sched_barrier(0);
  }

#pragma unroll
  for (int hh = 0; hh < 2; ++hh) {
    float l = lrun[hh];
    l += __shfl_xor(l, 16);
    l += __shfl_xor(l, 32);
    float linv = 1.0f / l;
    float linvR[4];
#pragma unroll
    for (int r = 0; r < 4; ++r) linvR[r] = __shfl(linv, g * 4 + r);
#pragma unroll
    for (int r = 0; r < 4; ++r) {
      int nseq = q0 + hh * 64 + w * 16 + g * 4 + r;
#pragma unroll
      for (int dt = 0; dt < 4; ++dt) {
        int d = dt * 16 + l15;
        AO[(size_t)(b * 1024 + nseq) * 1024 + h * 64 + d] = f2bf(oacc[hh][dt][r] * linvR[r]);
      }
    }
  }
}

extern "C" void kernel_launch(void* const* d_in, const int* in_sizes, int n_in,
                              void* d_out, int out_size, void* d_ws, size_t ws_size,
                              hipStream_t stream) {
  const float* x = (const float*)d_in[0];
  const float* qkv_w = (const float*)d_in[1];
  const float* qkv_b = (const float*)d_in[2];
  const float* proj_w = (const float*)d_in[3];
  const float* proj_b = (const float*)d_in[4];
  float* out = (float*)d_out;

  char* ws = (char*)d_ws;
  size_t off = 0;
  auto alloc = [&](size_t bytes) -> void* {
    void* p = ws + off;
    off += (bytes + 255) & ~(size_t)255;
    return p;
  };
  ushort* xb = (ushort*)alloc(4096ull * 1024 * 2);
  ushort* wqkvb = (ushort*)alloc(3072ull * 1024 * 2);
  ushort* wprojb = (ushort*)alloc(1024ull * 1024 * 2);
  ushort* Qb = (ushort*)alloc(64ull * 1024 * 64 * 2);
  ushort* Kb = (ushort*)alloc(64ull * 1024 * 64 * 2);
  ushort* Vt = (ushort*)alloc(64ull * 1024 * 64 * 2);
  ushort* AO = (ushort*)alloc(4096ull * 1024 * 2);
  float2* tab = (float2*)alloc(1024ull * 32 * sizeof(float2));

  cast_all<<<2048, 256, 0, stream>>>(x, qkv_w, proj_w, xb, wqkvb, wprojb, tab);

  gemm_qkv<<<768, 256, 0, stream>>>(xb, wqkvb, qkv_b, tab, Qb, Kb, Vt);

  attn<<<512, 256, 0, stream>>>(Qb, Kb, Vt, AO);

  gemm_proj<<<256, 256, 0, stream>>>(AO, wprojb, proj_b, out);
}

// Round 17
// 91.050 us; speedup vs baseline: 1.6098x; 1.6098x over previous
//
#include <hip/hip_runtime.h>
#include <hip/hip_bf16.h>
#include <stdint.h>

#define DEVI __device__ __forceinline__

typedef __attribute__((ext_vector_type(8))) short short8;
typedef __attribute__((ext_vector_type(4))) short short4v;
typedef __attribute__((ext_vector_type(4))) float floatx4;

DEVI ushort f2bf(float f) {
  union { float f; uint32_t u; } v; v.f = f;
  uint32_t u = v.u;
  uint32_t r = (u + 0x7FFFu + ((u >> 16) & 1u)) >> 16;
  return (ushort)r;
}
DEVI ushort f2bf_fast(float f) {
  union { float f; uint32_t u; } v; v.f = f;
  return (ushort)((v.u + 0x8000u) >> 16);
}
DEVI float bf2f(ushort h) {
  union { uint32_t u; float f; } v; v.u = ((uint32_t)h) << 16;
  return v.f;
}
DEVI void gld_lds16(const void* g, void* l) {
  __builtin_amdgcn_global_load_lds(
      (const __attribute__((address_space(1))) unsigned int*)g,
      (__attribute__((address_space(3))) unsigned int*)l, 16, 0, 0);
}

// ------- fused cast fp32 -> bf16 (x, qkv_w, proj_w) + RoPE table -------
__global__ __launch_bounds__(256, 4) void cast_all(
    const float* __restrict__ x, const float* __restrict__ w1,
    const float* __restrict__ w2, ushort* __restrict__ xb,
    ushort* __restrict__ w1b, ushort* __restrict__ w2b,
    float2* __restrict__ tab) {
  const int N1 = 4096 * 1024, N2 = 3072 * 1024, N3 = 1024 * 1024;
  int id = blockIdx.x * 256 + threadIdx.x;
  if (id < 32768) {  // RoPE cos/sin table: 1024 positions x 32 freq pairs
    int j = id & 31, n = id >> 5;
    float inv = powf(10000.0f, -(float)(2 * j) / 64.0f);
    float fr = (float)n * inv;
    tab[id] = make_float2(cosf(fr), sinf(fr));
  }
  int i = id * 4;
  const int total = N1 + N2 + N3;
  int stride = gridDim.x * 256 * 4;
  for (; i < total; i += stride) {
    const float* src; ushort* dst; int off;
    if (i < N1) { src = x; dst = xb; off = i; }
    else if (i < N1 + N2) { src = w1; dst = w1b; off = i - N1; }
    else { src = w2; dst = w2b; off = i - N1 - N2; }
    float4 v = *(const float4*)(src + off);
    ushort4 o;
    o.x = f2bf(v.x); o.y = f2bf(v.y); o.z = f2bf(v.z); o.w = f2bf(v.w);
    *(ushort4*)(dst + off) = o;
  }
}

// ---------------- GEMM1: qkv = x @ W^T + b, fused RoPE + scatter ----------
// r15 K-loop (2-phase dbuf, BK=32, 128^2, conflict-free swizzle, XCD swizzle,
// grid 768). Epilogues all LDS-packed for coalesced wide stores:
//   role 2 (V): transpose via T stride-264 -> Vt (b,h,d,n)    [r15-proven]
//   role 0/1 (Q/K): RoPE in regs, pack via T stride-272 -> 128B/thread runs
__global__ __launch_bounds__(256, 4) void gemm_qkv(
    const ushort* __restrict__ A, const ushort* __restrict__ Bm,
    const float* __restrict__ bias, const float2* __restrict__ tab,
    ushort* __restrict__ Qb, ushort* __restrict__ Kb,
    ushort* __restrict__ Vt) {
  __shared__ __align__(16) char pool[34816];  // K-loop 32KB; epi T <= 34816
  char* AsP = pool;            // [2][8192]: 128 rows x 64 B per buf
  char* BsP = pool + 16384;    // [2][8192]
  const int tid = threadIdx.x;
  const int w = tid >> 6, lane = tid & 63;

  // XCD swizzle: grid 768 = 32 mt x 24 nt, XCD region 8mt x 12nt
  const int bid = blockIdx.x;
  const int xcd = bid & 7, i5 = bid >> 3;       // i5 in [0,96)
  const int lm = i5 & 7, ln = i5 >> 3;          // 8 x 12
  const int mt = (xcd & 3) * 8 + lm;            // [0,32)
  const int nt = (xcd >> 2) * 12 + ln;          // [0,24)
  const int m0 = mt * 128, n0 = nt * 128;

  const int wm = (w >> 1) * 64, wn = (w & 1) * 64;
  const int lrow = lane & 15, g = lane >> 4;
  const int swrd = (g ^ ((lrow >> 1) & 3)) << 4;  // read-side swizzled chunk

  // staging source pre-swizzled: chunk' = (lane&3) ^ ((lane>>3)&3)
  const int swsrc = (((lane & 3) ^ ((lane >> 3) & 3)) << 4);
  const char* aG = (const char*)A + (size_t)(m0 + w * 32 + (lane >> 2)) * 2048 + swsrc;
  const char* bG = (const char*)Bm + (size_t)(n0 + w * 32 + (lane >> 2)) * 2048 + swsrc;
  const int ldst = w * 2048 + lane * 16;

  auto STAGE = [&](const int buf) {
    gld_lds16(aG, AsP + buf * 8192 + ldst);
    gld_lds16(aG + 16 * 2048, AsP + buf * 8192 + ldst + 1024);
    gld_lds16(bG, BsP + buf * 8192 + ldst);
    gld_lds16(bG + 16 * 2048, BsP + buf * 8192 + ldst + 1024);
    aG += 64; bG += 64;  // advance K by 32 elements
  };

  floatx4 acc[4][4] = {};

  auto TILE = [&](const int buf) {
    short8 af[4], bf[4];
#pragma unroll
    for (int t = 0; t < 4; ++t) {
      af[t] = *(const short8*)(AsP + buf * 8192 + (wm + t * 16 + lrow) * 64 + swrd);
      bf[t] = *(const short8*)(BsP + buf * 8192 + (wn + t * 16 + lrow) * 64 + swrd);
    }
#pragma unroll
    for (int i = 0; i < 4; ++i)
#pragma unroll
      for (int j = 0; j < 4; ++j)
        acc[i][j] = __builtin_amdgcn_mfma_f32_16x16x32_bf16(af[i], bf[j], acc[i][j], 0, 0, 0);
  };

  STAGE(0);
  asm volatile("s_waitcnt vmcnt(0)" ::: "memory");
  __builtin_amdgcn_s_barrier();
  __builtin_amdgcn_sched_barrier(0);

  for (int t = 0; t < 32; t += 2) {
    STAGE(1);
    __builtin_amdgcn_sched_barrier(0);
    TILE(0);
    asm volatile("s_waitcnt vmcnt(0)" ::: "memory");
    __builtin_amdgcn_s_barrier();
    __builtin_amdgcn_sched_barrier(0);

    if (t + 2 < 32) STAGE(0);
    __builtin_amdgcn_sched_barrier(0);
    TILE(1);
    asm volatile("s_waitcnt vmcnt(0)" ::: "memory");
    __builtin_amdgcn_s_barrier();
    __builtin_amdgcn_sched_barrier(0);
  }

  const int role = n0 >> 10;  // 0=q, 1=k, 2=v (block cols never straddle)
  const int b = m0 >> 10, nbase = m0 & 1023;
  if (role == 2) {
    // ---- V path (r15-proven): LDS transpose -> direct Vt (b,h,d,n) ----
    char* T = pool;
#pragma unroll
    for (int i = 0; i < 4; ++i) {
      int lr0 = wm + i * 16 + g * 4;  // 4 consecutive local rows
#pragma unroll
      for (int j = 0; j < 4; ++j) {
        int lc = wn + j * 16 + lrow;
        float bv = bias[n0 + lc];
        ushort4 o;
#pragma unroll
        for (int r = 0; r < 4; ++r) ((ushort*)&o)[r] = f2bf(acc[i][j][r] + bv);
        *(ushort4*)(T + lc * 264 + lr0 * 2) = o;
      }
    }
    __syncthreads();
    const int h0 = (n0 - 2048) >> 6;
    const int c = tid >> 1, half = tid & 1;   // col 0..127, n-half 0..1
    const int h = h0 + (c >> 6), d = c & 63;
    ushort* dst = Vt + (size_t)(b * 16 + h) * 65536 + (size_t)d * 1024 + nbase + half * 64;
    const char* src = T + c * 264 + half * 128;
#pragma unroll
    for (int k = 0; k < 16; ++k)
      *(short4v*)(dst + k * 4) = *(const short4v*)(src + k * 8);
  } else {
    // ---- Q/K path: RoPE in regs, pack T[n_loc][c_loc] (272B rows), then
    // each thread stores one contiguous 128B run of (b,h,n,d) output ----
    const float sc = (1.0f / 64.0f) * 1.44269504088896f;  // scale^2 * log2(e)
    char* T = pool;
#pragma unroll
    for (int i = 0; i < 4; ++i) {
      int lr0 = wm + i * 16 + g * 4;
#pragma unroll
      for (int j = 0; j < 4; ++j) {
        int lc = wn + j * 16 + lrow;
        int ncol = n0 + lc;
        float bv = bias[ncol];
        int d = ncol & 63;
#pragma unroll
        for (int r = 0; r < 4; ++r) {
          float v = acc[i][j][r] + bv;
          int n = (nbase + lr0 + r);  // position within batch (m0 same b)
          float p = __shfl_xor(v, 1);  // partner col (d^1), same row
          float2 cs = tab[n * 32 + (d >> 1)];
          float o = (d & 1) ? (v * cs.x + p * cs.y) : (v * cs.x - p * cs.y);
          if (role == 0) o *= sc;
          *(ushort*)(T + (lr0 + r) * 272 + lc * 2) = f2bf(o);
        }
      }
    }
    __syncthreads();
    const int h0 = (n0 & 1023) >> 6;
    const int n_l = tid >> 1, half = tid & 1;  // local row, h-half
    ushort* dst = (role == 0 ? Qb : Kb) +
                  (size_t)(b * 16 + h0 + half) * 65536 + (size_t)(nbase + n_l) * 64;
    const char* src = T + n_l * 272 + half * 128;
#pragma unroll
    for (int k = 0; k < 8; ++k)
      *(short8*)(dst + k * 8) = *(const short8*)(src + k * 16);
  }
}

// ---------------- GEMM2: out = AO @ proj_w^T + b (fp32 out) ----------------
// r12 3-stage counted pipeline + swizzled conflict-free reads. Grid 256.
__global__ __launch_bounds__(256, 3) void gemm_proj(
    const ushort* __restrict__ A, const ushort* __restrict__ Bm,
    const float* __restrict__ bias, float* __restrict__ Cout) {
  __shared__ __align__(16) char lds[3][16384];
  char* L0 = &lds[0][0];
  const int tid = threadIdx.x;
  const int w = tid >> 6, lane = tid & 63;

  const int bid = blockIdx.x;
  const int xcd = bid & 7, i5 = bid >> 3;
  const int lm = i5 & 7, ln = i5 >> 3;
  const int mt = (xcd & 3) * 8 + lm;
  const int nt = (xcd >> 2) * 4 + ln;
  const int m0 = mt * 128, n0 = nt * 128;

  const int wm = (w >> 1) * 64, wn = (w & 1) * 64;
  const int lrow = lane & 15, g = lane >> 4;
  const int swrd = (g ^ ((lrow >> 1) & 3)) << 4;

  const int swsrc = (((lane & 3) ^ ((lane >> 3) & 3)) << 4);
  const char* aG = (const char*)A + (size_t)(m0 + w * 32 + (lane >> 2)) * 2048 + swsrc;
  const char* bG = (const char*)Bm + (size_t)(n0 + w * 32 + (lane >> 2)) * 2048 + swsrc;
  const int ldst = w * 2048 + lane * 16;

  auto STAGE = [&](const int base) {
    char* L = L0 + base;
    gld_lds16(aG, L + ldst);
    gld_lds16(aG + 16 * 2048, L + ldst + 1024);
    gld_lds16(bG, L + 8192 + ldst);
    gld_lds16(bG + 16 * 2048, L + 8192 + ldst + 1024);
    aG += 64; bG += 64;
  };

  floatx4 acc[4][4] = {};

  auto TILE = [&](const int base) {
    const char* L = L0 + base;
    short8 af[4], bf[4];
#pragma unroll
    for (int t = 0; t < 4; ++t) {
      af[t] = *(const short8*)(L + (wm + t * 16 + lrow) * 64 + swrd);
      bf[t] = *(const short8*)(L + 8192 + (wn + t * 16 + lrow) * 64 + swrd);
    }
#pragma unroll
    for (int i = 0; i < 4; ++i)
#pragma unroll
      for (int j = 0; j < 4; ++j)
        acc[i][j] = __builtin_amdgcn_mfma_f32_16x16x32_bf16(af[i], bf[j], acc[i][j], 0, 0, 0);
  };

  STAGE(0);
  STAGE(16384);
  int bT = 0, bS = 32768;

  for (int t = 0; t < 31; ++t) {
    asm volatile("s_waitcnt vmcnt(4)" ::: "memory");
    __builtin_amdgcn_s_barrier();
    __builtin_amdgcn_sched_barrier(0);
    if (t < 30) STAGE(bS);
    __builtin_amdgcn_sched_barrier(0);
    TILE(bT);
    __builtin_amdgcn_sched_barrier(0);
    bT += 16384; if (bT == 49152) bT = 0;
    bS += 16384; if (bS == 49152) bS = 0;
  }
  asm volatile("s_waitcnt vmcnt(0)" ::: "memory");
  __builtin_amdgcn_s_barrier();
  __builtin_amdgcn_sched_barrier(0);
  TILE(bT);

#pragma unroll
  for (int i = 0; i < 4; ++i) {
    int mrow = m0 + wm + i * 16 + (lane >> 4) * 4;
#pragma unroll
    for (int j = 0; j < 4; ++j) {
      int ncol = n0 + wn + j * 16 + (lane & 15);
      float bv = bias[ncol];
#pragma unroll
      for (int r = 0; r < 4; ++r)
        Cout[(size_t)(mrow + r) * 1024 + ncol] = acc[i][j][r] + bv;
    }
  }
}

// ---------------- Flash attention v5 (r15-proven, reverted from v6) --------
__global__ __launch_bounds__(256, 4) void attn(
    const ushort* __restrict__ Q, const ushort* __restrict__ Kc,
    const ushort* __restrict__ Vt, ushort* __restrict__ AO) {
  __shared__ char lds[2][16384];  // per buf: K tile 8KB @0, V tile 8KB @8192
  char* ldsbase = &lds[0][0];
  int id = blockIdx.x;
  int bh = id & 63, qi = id >> 6;
  int b = bh >> 4, h = bh & 15;
  int q0 = qi * 64;
  int tid = threadIdx.x, w = tid >> 6, lane = tid & 63;
  int l15 = lane & 15, g = lane >> 4;
  const ushort* Qbh = Q + (size_t)bh * 65536;
  const char* Kbh = (const char*)(Kc + (size_t)bh * 65536);
  const char* Vbh = (const char*)(Vt + (size_t)bh * 65536);

  short8 qf[2];
#pragma unroll
  for (int ks = 0; ks < 2; ++ks)
    qf[ks] = *(const short8*)(Qbh + (size_t)(q0 + w * 16 + l15) * 64 + ks * 32 + g * 8);

  int kaddr[8];
#pragma unroll
  for (int ks = 0; ks < 2; ++ks)
#pragma unroll
    for (int nt = 0; nt < 4; ++nt) {
      int row = nt * 16 + l15;
      kaddr[ks * 4 + nt] = (row * 128 + ks * 64 + g * 16) ^ ((row & 7) << 4);
    }
  int vaddr[16];
#pragma unroll
  for (int ch = 0; ch < 2; ++ch)
#pragma unroll
    for (int dt = 0; dt < 4; ++dt)
#pragma unroll
      for (int hf = 0; hf < 2; ++hf) {
        int row = dt * 16 + l15;
        vaddr[(ch * 4 + dt) * 2 + hf] =
            8192 + ((row * 128 + ch * 64 + hf * 32 + g * 8) ^ ((row & 7) << 4));
      }

  const int d0 = w * 2048 + lane * 16;
  const int d1 = d0 + 1024;
  const int r0 = d0 >> 7, r1 = d1 >> 7;
  const int s0 = d0 ^ ((r0 & 7) << 4), s1 = d1 ^ ((r1 & 7) << 4);
  const char* pK0 = Kbh + s0;
  const char* pK1 = Kbh + s1;
  const char* pV0 = Vbh + r0 * 2048 + (s0 & 127);
  const char* pV1 = Vbh + r1 * 2048 + (s1 & 127);

  auto STAGE = [&](const int B) {
    gld_lds16(pK0, ldsbase + B + d0);
    gld_lds16(pK1, ldsbase + B + d1);
    gld_lds16(pV0, ldsbase + B + 8192 + d0);
    gld_lds16(pV1, ldsbase + B + 8192 + d1);
    pK0 += 8192; pK1 += 8192; pV0 += 128; pV1 += 128;
  };

  floatx4 oacc[4] = {};
  float lrun = 0.f;

  auto TILE = [&](const int B) {
    floatx4 sacc[4] = {};
    __builtin_amdgcn_s_setprio(1);
#pragma unroll
    for (int ks = 0; ks < 2; ++ks) {
      short8 kf[4];
#pragma unroll
      for (int nt = 0; nt < 4; ++nt)
        kf[nt] = *(const short8*)(ldsbase + B + kaddr[ks * 4 + nt]);
#pragma unroll
      for (int nt = 0; nt < 4; ++nt)
        sacc[nt] = __builtin_amdgcn_mfma_f32_16x16x32_bf16(kf[nt], qf[ks], sacc[nt], 0, 0, 0);
    }
    __builtin_amdgcn_s_setprio(0);

    float rs = 0.f;
#pragma unroll
    for (int nt = 0; nt < 4; ++nt)
#pragma unroll
      for (int r = 0; r < 4; ++r) {
        float p = __builtin_amdgcn_exp2f(sacc[nt][r]);
        sacc[nt][r] = p;
        rs += p;
      }
    lrun += rs;

    short8 pa[2];
#pragma unroll
    for (int ch = 0; ch < 2; ++ch)
#pragma unroll
      for (int r = 0; r < 4; ++r) {
        pa[ch][r] = (short)f2bf_fast(sacc[2 * ch][r]);
        pa[ch][r + 4] = (short)f2bf_fast(sacc[2 * ch + 1][r]);
      }

    __builtin_amdgcn_s_setprio(1);
#pragma unroll
    for (int ch = 0; ch < 2; ++ch)
#pragma unroll
      for (int dt = 0; dt < 4; ++dt) {
        short4v va = *(const short4v*)(ldsbase + B + vaddr[(ch * 4 + dt) * 2]);
        short4v vb = *(const short4v*)(ldsbase + B + vaddr[(ch * 4 + dt) * 2 + 1]);
        short8 vf = __builtin_shufflevector(va, vb, 0, 1, 2, 3, 4, 5, 6, 7);
        oacc[dt] = __builtin_amdgcn_mfma_f32_16x16x32_bf16(pa[ch], vf, oacc[dt], 0, 0, 0);
      }
    __builtin_amdgcn_s_setprio(0);
  };

  STAGE(0);
  asm volatile("s_waitcnt vmcnt(0)" ::: "memory");
  __builtin_amdgcn_s_barrier();
  __builtin_amdgcn_sched_barrier(0);

  for (int kt = 0; kt < 16; kt += 2) {
    STAGE(16384);
    __builtin_amdgcn_sched_barrier(0);
    TILE(0);
    asm volatile("s_waitcnt vmcnt(0)" ::: "memory");
    __builtin_amdgcn_s_barrier();
    __builtin_amdgcn_sched_barrier(0);

    if (kt + 2 < 16) STAGE(0);
    __builtin_amdgcn_sched_barrier(0);
    TILE(16384);
    asm volatile("s_waitcnt vmcnt(0)" ::: "memory");
    __builtin_amdgcn_s_barrier();
    __builtin_amdgcn_sched_barrier(0);
  }

  lrun += __shfl_xor(lrun, 16);
  lrun += __shfl_xor(lrun, 32);
  float linv = 1.0f / lrun;
  float linvR[4];
#pragma unroll
  for (int r = 0; r < 4; ++r) linvR[r] = __shfl(linv, g * 4 + r);
#pragma unroll
  for (int r = 0; r < 4; ++r) {
    int nseq = q0 + w * 16 + g * 4 + r;
#pragma unroll
    for (int dt = 0; dt < 4; ++dt) {
      int d = dt * 16 + l15;
      AO[(size_t)(b * 1024 + nseq) * 1024 + h * 64 + d] = f2bf(oacc[dt][r] * linvR[r]);
    }
  }
}

extern "C" void kernel_launch(void* const* d_in, const int* in_sizes, int n_in,
                              void* d_out, int out_size, void* d_ws, size_t ws_size,
                              hipStream_t stream) {
  const float* x = (const float*)d_in[0];
  const float* qkv_w = (const float*)d_in[1];
  const float* qkv_b = (const float*)d_in[2];
  const float* proj_w = (const float*)d_in[3];
  const float* proj_b = (const float*)d_in[4];
  float* out = (float*)d_out;

  char* ws = (char*)d_ws;
  size_t off = 0;
  auto alloc = [&](size_t bytes) -> void* {
    void* p = ws + off;
    off += (bytes + 255) & ~(size_t)255;
    return p;
  };
  ushort* xb = (ushort*)alloc(4096ull * 1024 * 2);
  ushort* wqkvb = (ushort*)alloc(3072ull * 1024 * 2);
  ushort* wprojb = (ushort*)alloc(1024ull * 1024 * 2);
  ushort* Qb = (ushort*)alloc(64ull * 1024 * 64 * 2);
  ushort* Kb = (ushort*)alloc(64ull * 1024 * 64 * 2);
  ushort* Vt = (ushort*)alloc(64ull * 1024 * 64 * 2);
  ushort* AO = (ushort*)alloc(4096ull * 1024 * 2);
  float2* tab = (float2*)alloc(1024ull * 32 * sizeof(float2));

  cast_all<<<2048, 256, 0, stream>>>(x, qkv_w, proj_w, xb, wqkvb, wprojb, tab);

  gemm_qkv<<<768, 256, 0, stream>>>(xb, wqkvb, qkv_b, tab, Qb, Kb, Vt);

  attn<<<1024, 256, 0, stream>>>(Qb, Kb, Vt, AO);

  gemm_proj<<<256, 256, 0, stream>>>(AO, wprojb, proj_b, out);
}

// Round 18
// 85.920 us; speedup vs baseline: 1.7059x; 1.0597x over previous
//
#include <hip/hip_runtime.h>
#include <hip/hip_bf16.h>
#include <stdint.h>

#define DEVI __device__ __forceinline__

typedef __attribute__((ext_vector_type(8))) short short8;
typedef __attribute__((ext_vector_type(4))) short short4v;
typedef __attribute__((ext_vector_type(4))) float floatx4;

DEVI ushort f2bf(float f) {
  union { float f; uint32_t u; } v; v.f = f;
  uint32_t u = v.u;
  uint32_t r = (u + 0x7FFFu + ((u >> 16) & 1u)) >> 16;
  return (ushort)r;
}
DEVI ushort f2bf_fast(float f) {
  union { float f; uint32_t u; } v; v.f = f;
  return (ushort)((v.u + 0x8000u) >> 16);
}
DEVI float bf2f(ushort h) {
  union { uint32_t u; float f; } v; v.u = ((uint32_t)h) << 16;
  return v.f;
}
DEVI void gld_lds16(const void* g, void* l) {
  __builtin_amdgcn_global_load_lds(
      (const __attribute__((address_space(1))) unsigned int*)g,
      (__attribute__((address_space(3))) unsigned int*)l, 16, 0, 0);
}

// ------- fused cast fp32 -> bf16 (x, qkv_w, proj_w) + RoPE table -------
__global__ __launch_bounds__(256, 4) void cast_all(
    const float* __restrict__ x, const float* __restrict__ w1,
    const float* __restrict__ w2, ushort* __restrict__ xb,
    ushort* __restrict__ w1b, ushort* __restrict__ w2b,
    float2* __restrict__ tab) {
  const int N1 = 4096 * 1024, N2 = 3072 * 1024, N3 = 1024 * 1024;
  int id = blockIdx.x * 256 + threadIdx.x;
  if (id < 32768) {  // RoPE cos/sin table: 1024 positions x 32 freq pairs
    int j = id & 31, n = id >> 5;
    float inv = powf(10000.0f, -(float)(2 * j) / 64.0f);
    float fr = (float)n * inv;
    tab[id] = make_float2(cosf(fr), sinf(fr));
  }
  int i = id * 4;
  const int total = N1 + N2 + N3;
  int stride = gridDim.x * 256 * 4;
  for (; i < total; i += stride) {
    const float* src; ushort* dst; int off;
    if (i < N1) { src = x; dst = xb; off = i; }
    else if (i < N1 + N2) { src = w1; dst = w1b; off = i - N1; }
    else { src = w2; dst = w2b; off = i - N1 - N2; }
    float4 v = *(const float4*)(src + off);
    ushort4 o;
    o.x = f2bf(v.x); o.y = f2bf(v.y); o.z = f2bf(v.z); o.w = f2bf(v.w);
    *(ushort4*)(dst + off) = o;
  }
}

// ---------------- GEMM1: qkv = x @ W^T + b, fused RoPE + scatter ----------
// r15 measured-best: 2-phase dbuf K-loop (BK=32, 128^2, conflict-free
// swizzle, XCD swizzle, grid 768). Epilogues:
//   role 2 (V): LDS transpose (stride 264) -> direct Vt (b,h,d,n)  [+6.7us]
//   role 0/1 (Q/K): scalar RoPE scatter (LDS-pack variant tested r17: -4us)
__global__ __launch_bounds__(256, 4) void gemm_qkv(
    const ushort* __restrict__ A, const ushort* __restrict__ Bm,
    const float* __restrict__ bias, const float2* __restrict__ tab,
    ushort* __restrict__ Qb, ushort* __restrict__ Kb,
    ushort* __restrict__ Vt) {
  __shared__ __align__(16) char pool[33792];  // K-loop 32KB; epi T 33KB
  char* AsP = pool;            // [2][8192]: 128 rows x 64 B per buf
  char* BsP = pool + 16384;    // [2][8192]
  const int tid = threadIdx.x;
  const int w = tid >> 6, lane = tid & 63;

  // XCD swizzle: grid 768 = 32 mt x 24 nt, XCD region 8mt x 12nt
  const int bid = blockIdx.x;
  const int xcd = bid & 7, i5 = bid >> 3;       // i5 in [0,96)
  const int lm = i5 & 7, ln = i5 >> 3;          // 8 x 12
  const int mt = (xcd & 3) * 8 + lm;            // [0,32)
  const int nt = (xcd >> 2) * 12 + ln;          // [0,24)
  const int m0 = mt * 128, n0 = nt * 128;

  const int wm = (w >> 1) * 64, wn = (w & 1) * 64;
  const int lrow = lane & 15, g = lane >> 4;
  const int swrd = (g ^ ((lrow >> 1) & 3)) << 4;  // read-side swizzled chunk

  // staging source pre-swizzled: chunk' = (lane&3) ^ ((lane>>3)&3)
  const int swsrc = (((lane & 3) ^ ((lane >> 3) & 3)) << 4);
  const char* aG = (const char*)A + (size_t)(m0 + w * 32 + (lane >> 2)) * 2048 + swsrc;
  const char* bG = (const char*)Bm + (size_t)(n0 + w * 32 + (lane >> 2)) * 2048 + swsrc;
  const int ldst = w * 2048 + lane * 16;

  auto STAGE = [&](const int buf) {
    gld_lds16(aG, AsP + buf * 8192 + ldst);
    gld_lds16(aG + 16 * 2048, AsP + buf * 8192 + ldst + 1024);
    gld_lds16(bG, BsP + buf * 8192 + ldst);
    gld_lds16(bG + 16 * 2048, BsP + buf * 8192 + ldst + 1024);
    aG += 64; bG += 64;  // advance K by 32 elements
  };

  floatx4 acc[4][4] = {};

  auto TILE = [&](const int buf) {
    short8 af[4], bf[4];
#pragma unroll
    for (int t = 0; t < 4; ++t) {
      af[t] = *(const short8*)(AsP + buf * 8192 + (wm + t * 16 + lrow) * 64 + swrd);
      bf[t] = *(const short8*)(BsP + buf * 8192 + (wn + t * 16 + lrow) * 64 + swrd);
    }
#pragma unroll
    for (int i = 0; i < 4; ++i)
#pragma unroll
      for (int j = 0; j < 4; ++j)
        acc[i][j] = __builtin_amdgcn_mfma_f32_16x16x32_bf16(af[i], bf[j], acc[i][j], 0, 0, 0);
  };

  STAGE(0);
  asm volatile("s_waitcnt vmcnt(0)" ::: "memory");
  __builtin_amdgcn_s_barrier();
  __builtin_amdgcn_sched_barrier(0);

  for (int t = 0; t < 32; t += 2) {
    STAGE(1);
    __builtin_amdgcn_sched_barrier(0);
    TILE(0);
    asm volatile("s_waitcnt vmcnt(0)" ::: "memory");
    __builtin_amdgcn_s_barrier();
    __builtin_amdgcn_sched_barrier(0);

    if (t + 2 < 32) STAGE(0);
    __builtin_amdgcn_sched_barrier(0);
    TILE(1);
    asm volatile("s_waitcnt vmcnt(0)" ::: "memory");
    __builtin_amdgcn_s_barrier();
    __builtin_amdgcn_sched_barrier(0);
  }

  const int role = n0 >> 10;  // 0=q, 1=k, 2=v (block cols never straddle)
  const int b = m0 >> 10, nbase = m0 & 1023;
  if (role == 2) {
    // ---- V path: LDS transpose -> direct Vt (b,h,d,n) write ----
    char* T = pool;
#pragma unroll
    for (int i = 0; i < 4; ++i) {
      int lr0 = wm + i * 16 + g * 4;  // 4 consecutive local rows
#pragma unroll
      for (int j = 0; j < 4; ++j) {
        int lc = wn + j * 16 + lrow;
        float bv = bias[n0 + lc];
        ushort4 o;
#pragma unroll
        for (int r = 0; r < 4; ++r) ((ushort*)&o)[r] = f2bf(acc[i][j][r] + bv);
        *(ushort4*)(T + lc * 264 + lr0 * 2) = o;
      }
    }
    __syncthreads();
    const int h0 = (n0 - 2048) >> 6;
    const int c = tid >> 1, half = tid & 1;   // col 0..127, n-half 0..1
    const int h = h0 + (c >> 6), d = c & 63;
    ushort* dst = Vt + (size_t)(b * 16 + h) * 65536 + (size_t)d * 1024 + nbase + half * 64;
    const char* src = T + c * 264 + half * 128;
#pragma unroll
    for (int k = 0; k < 16; ++k)
      *(short4v*)(dst + k * 4) = *(const short4v*)(src + k * 8);
  } else {
    // ---- Q/K path: scalar RoPE scatter (r15-proven best) ----
    const float sc = (1.0f / 64.0f) * 1.44269504088896f;  // scale^2 * log2(e)
#pragma unroll
    for (int i = 0; i < 4; ++i) {
      int mrow = m0 + wm + i * 16 + g * 4;
#pragma unroll
      for (int j = 0; j < 4; ++j) {
        int ncol = n0 + wn + j * 16 + lrow;
        float bv = bias[ncol];
        int cm = ncol & 1023;
        int h = cm >> 6, d = cm & 63;
#pragma unroll
        for (int r = 0; r < 4; ++r) {
          float v = acc[i][j][r] + bv;
          int row = mrow + r;
          int bb = row >> 10, n = row & 1023;
          float p = __shfl_xor(v, 1);  // partner col (d^1), same row
          float2 cs = tab[n * 32 + (d >> 1)];
          float o = (d & 1) ? (v * cs.x + p * cs.y) : (v * cs.x - p * cs.y);
          if (role == 0) o *= sc;
          ushort* dstqk = (role == 0) ? Qb : Kb;
          dstqk[((size_t)(bb * 16 + h) * 1024 + n) * 64 + d] = f2bf(o);
        }
      }
    }
  }
}

// ---------------- GEMM2: out = AO @ proj_w^T + b (fp32 out) ----------------
// r12 3-stage counted pipeline + swizzled conflict-free reads. Grid 256.
__global__ __launch_bounds__(256, 3) void gemm_proj(
    const ushort* __restrict__ A, const ushort* __restrict__ Bm,
    const float* __restrict__ bias, float* __restrict__ Cout) {
  __shared__ __align__(16) char lds[3][16384];
  char* L0 = &lds[0][0];
  const int tid = threadIdx.x;
  const int w = tid >> 6, lane = tid & 63;

  const int bid = blockIdx.x;
  const int xcd = bid & 7, i5 = bid >> 3;
  const int lm = i5 & 7, ln = i5 >> 3;
  const int mt = (xcd & 3) * 8 + lm;
  const int nt = (xcd >> 2) * 4 + ln;
  const int m0 = mt * 128, n0 = nt * 128;

  const int wm = (w >> 1) * 64, wn = (w & 1) * 64;
  const int lrow = lane & 15, g = lane >> 4;
  const int swrd = (g ^ ((lrow >> 1) & 3)) << 4;

  const int swsrc = (((lane & 3) ^ ((lane >> 3) & 3)) << 4);
  const char* aG = (const char*)A + (size_t)(m0 + w * 32 + (lane >> 2)) * 2048 + swsrc;
  const char* bG = (const char*)Bm + (size_t)(n0 + w * 32 + (lane >> 2)) * 2048 + swsrc;
  const int ldst = w * 2048 + lane * 16;

  auto STAGE = [&](const int base) {
    char* L = L0 + base;
    gld_lds16(aG, L + ldst);
    gld_lds16(aG + 16 * 2048, L + ldst + 1024);
    gld_lds16(bG, L + 8192 + ldst);
    gld_lds16(bG + 16 * 2048, L + 8192 + ldst + 1024);
    aG += 64; bG += 64;
  };

  floatx4 acc[4][4] = {};

  auto TILE = [&](const int base) {
    const char* L = L0 + base;
    short8 af[4], bf[4];
#pragma unroll
    for (int t = 0; t < 4; ++t) {
      af[t] = *(const short8*)(L + (wm + t * 16 + lrow) * 64 + swrd);
      bf[t] = *(const short8*)(L + 8192 + (wn + t * 16 + lrow) * 64 + swrd);
    }
#pragma unroll
    for (int i = 0; i < 4; ++i)
#pragma unroll
      for (int j = 0; j < 4; ++j)
        acc[i][j] = __builtin_amdgcn_mfma_f32_16x16x32_bf16(af[i], bf[j], acc[i][j], 0, 0, 0);
  };

  STAGE(0);
  STAGE(16384);
  int bT = 0, bS = 32768;

  for (int t = 0; t < 31; ++t) {
    asm volatile("s_waitcnt vmcnt(4)" ::: "memory");
    __builtin_amdgcn_s_barrier();
    __builtin_amdgcn_sched_barrier(0);
    if (t < 30) STAGE(bS);
    __builtin_amdgcn_sched_barrier(0);
    TILE(bT);
    __builtin_amdgcn_sched_barrier(0);
    bT += 16384; if (bT == 49152) bT = 0;
    bS += 16384; if (bS == 49152) bS = 0;
  }
  asm volatile("s_waitcnt vmcnt(0)" ::: "memory");
  __builtin_amdgcn_s_barrier();
  __builtin_amdgcn_sched_barrier(0);
  TILE(bT);

#pragma unroll
  for (int i = 0; i < 4; ++i) {
    int mrow = m0 + wm + i * 16 + (lane >> 4) * 4;
#pragma unroll
    for (int j = 0; j < 4; ++j) {
      int ncol = n0 + wn + j * 16 + (lane & 15);
      float bv = bias[ncol];
#pragma unroll
      for (int r = 0; r < 4; ++r)
        Cout[(size_t)(mrow + r) * 1024 + ncol] = acc[i][j][r] + bv;
    }
  }
}

// ---------------- Flash attention v5 (r15-proven) ----------------
__global__ __launch_bounds__(256, 4) void attn(
    const ushort* __restrict__ Q, const ushort* __restrict__ Kc,
    const ushort* __restrict__ Vt, ushort* __restrict__ AO) {
  __shared__ char lds[2][16384];  // per buf: K tile 8KB @0, V tile 8KB @8192
  char* ldsbase = &lds[0][0];
  int id = blockIdx.x;
  int bh = id & 63, qi = id >> 6;
  int b = bh >> 4, h = bh & 15;
  int q0 = qi * 64;
  int tid = threadIdx.x, w = tid >> 6, lane = tid & 63;
  int l15 = lane & 15, g = lane >> 4;
  const ushort* Qbh = Q + (size_t)bh * 65536;
  const char* Kbh = (const char*)(Kc + (size_t)bh * 65536);
  const char* Vbh = (const char*)(Vt + (size_t)bh * 65536);

  short8 qf[2];
#pragma unroll
  for (int ks = 0; ks < 2; ++ks)
    qf[ks] = *(const short8*)(Qbh + (size_t)(q0 + w * 16 + l15) * 64 + ks * 32 + g * 8);

  int kaddr[8];
#pragma unroll
  for (int ks = 0; ks < 2; ++ks)
#pragma unroll
    for (int nt = 0; nt < 4; ++nt) {
      int row = nt * 16 + l15;
      kaddr[ks * 4 + nt] = (row * 128 + ks * 64 + g * 16) ^ ((row & 7) << 4);
    }
  int vaddr[16];
#pragma unroll
  for (int ch = 0; ch < 2; ++ch)
#pragma unroll
    for (int dt = 0; dt < 4; ++dt)
#pragma unroll
      for (int hf = 0; hf < 2; ++hf) {
        int row = dt * 16 + l15;
        vaddr[(ch * 4 + dt) * 2 + hf] =
            8192 + ((row * 128 + ch * 64 + hf * 32 + g * 8) ^ ((row & 7) << 4));
      }

  const int d0 = w * 2048 + lane * 16;
  const int d1 = d0 + 1024;
  const int r0 = d0 >> 7, r1 = d1 >> 7;
  const int s0 = d0 ^ ((r0 & 7) << 4), s1 = d1 ^ ((r1 & 7) << 4);
  const char* pK0 = Kbh + s0;
  const char* pK1 = Kbh + s1;
  const char* pV0 = Vbh + r0 * 2048 + (s0 & 127);
  const char* pV1 = Vbh + r1 * 2048 + (s1 & 127);

  auto STAGE = [&](const int B) {
    gld_lds16(pK0, ldsbase + B + d0);
    gld_lds16(pK1, ldsbase + B + d1);
    gld_lds16(pV0, ldsbase + B + 8192 + d0);
    gld_lds16(pV1, ldsbase + B + 8192 + d1);
    pK0 += 8192; pK1 += 8192; pV0 += 128; pV1 += 128;
  };

  floatx4 oacc[4] = {};
  float lrun = 0.f;

  auto TILE = [&](const int B) {
    floatx4 sacc[4] = {};
    __builtin_amdgcn_s_setprio(1);
#pragma unroll
    for (int ks = 0; ks < 2; ++ks) {
      short8 kf[4];
#pragma unroll
      for (int nt = 0; nt < 4; ++nt)
        kf[nt] = *(const short8*)(ldsbase + B + kaddr[ks * 4 + nt]);
#pragma unroll
      for (int nt = 0; nt < 4; ++nt)
        sacc[nt] = __builtin_amdgcn_mfma_f32_16x16x32_bf16(kf[nt], qf[ks], sacc[nt], 0, 0, 0);
    }
    __builtin_amdgcn_s_setprio(0);

    float rs = 0.f;
#pragma unroll
    for (int nt = 0; nt < 4; ++nt)
#pragma unroll
      for (int r = 0; r < 4; ++r) {
        float p = __builtin_amdgcn_exp2f(sacc[nt][r]);
        sacc[nt][r] = p;
        rs += p;
      }
    lrun += rs;

    short8 pa[2];
#pragma unroll
    for (int ch = 0; ch < 2; ++ch)
#pragma unroll
      for (int r = 0; r < 4; ++r) {
        pa[ch][r] = (short)f2bf_fast(sacc[2 * ch][r]);
        pa[ch][r + 4] = (short)f2bf_fast(sacc[2 * ch + 1][r]);
      }

    __builtin_amdgcn_s_setprio(1);
#pragma unroll
    for (int ch = 0; ch < 2; ++ch)
#pragma unroll
      for (int dt = 0; dt < 4; ++dt) {
        short4v va = *(const short4v*)(ldsbase + B + vaddr[(ch * 4 + dt) * 2]);
        short4v vb = *(const short4v*)(ldsbase + B + vaddr[(ch * 4 + dt) * 2 + 1]);
        short8 vf = __builtin_shufflevector(va, vb, 0, 1, 2, 3, 4, 5, 6, 7);
        oacc[dt] = __builtin_amdgcn_mfma_f32_16x16x32_bf16(pa[ch], vf, oacc[dt], 0, 0, 0);
      }
    __builtin_amdgcn_s_setprio(0);
  };

  STAGE(0);
  asm volatile("s_waitcnt vmcnt(0)" ::: "memory");
  __builtin_amdgcn_s_barrier();
  __builtin_amdgcn_sched_barrier(0);

  for (int kt = 0; kt < 16; kt += 2) {
    STAGE(16384);
    __builtin_amdgcn_sched_barrier(0);
    TILE(0);
    asm volatile("s_waitcnt vmcnt(0)" ::: "memory");
    __builtin_amdgcn_s_barrier();
    __builtin_amdgcn_sched_barrier(0);

    if (kt + 2 < 16) STAGE(0);
    __builtin_amdgcn_sched_barrier(0);
    TILE(16384);
    asm volatile("s_waitcnt vmcnt(0)" ::: "memory");
    __builtin_amdgcn_s_barrier();
    __builtin_amdgcn_sched_barrier(0);
  }

  lrun += __shfl_xor(lrun, 16);
  lrun += __shfl_xor(lrun, 32);
  float linv = 1.0f / lrun;
  float linvR[4];
#pragma unroll
  for (int r = 0; r < 4; ++r) linvR[r] = __shfl(linv, g * 4 + r);
#pragma unroll
  for (int r = 0; r < 4; ++r) {
    int nseq = q0 + w * 16 + g * 4 + r;
#pragma unroll
    for (int dt = 0; dt < 4; ++dt) {
      int d = dt * 16 + l15;
      AO[(size_t)(b * 1024 + nseq) * 1024 + h * 64 + d] = f2bf(oacc[dt][r] * linvR[r]);
    }
  }
}

extern "C" void kernel_launch(void* const* d_in, const int* in_sizes, int n_in,
                              void* d_out, int out_size, void* d_ws, size_t ws_size,
                              hipStream_t stream) {
  const float* x = (const float*)d_in[0];
  const float* qkv_w = (const float*)d_in[1];
  const float* qkv_b = (const float*)d_in[2];
  const float* proj_w = (const float*)d_in[3];
  const float* proj_b = (const float*)d_in[4];
  float* out = (float*)d_out;

  char* ws = (char*)d_ws;
  size_t off = 0;
  auto alloc = [&](size_t bytes) -> void* {
    void* p = ws + off;
    off += (bytes + 255) & ~(size_t)255;
    return p;
  };
  ushort* xb = (ushort*)alloc(4096ull * 1024 * 2);
  ushort* wqkvb = (ushort*)alloc(3072ull * 1024 * 2);
  ushort* wprojb = (ushort*)alloc(1024ull * 1024 * 2);
  ushort* Qb = (ushort*)alloc(64ull * 1024 * 64 * 2);
  ushort* Kb = (ushort*)alloc(64ull * 1024 * 64 * 2);
  ushort* Vt = (ushort*)alloc(64ull * 1024 * 64 * 2);
  ushort* AO = (ushort*)alloc(4096ull * 1024 * 2);
  float2* tab = (float2*)alloc(1024ull * 32 * sizeof(float2));

  cast_all<<<2048, 256, 0, stream>>>(x, qkv_w, proj_w, xb, wqkvb, wprojb, tab);

  gemm_qkv<<<768, 256, 0, stream>>>(xb, wqkvb, qkv_b, tab, Qb, Kb, Vt);

  attn<<<1024, 256, 0, stream>>>(Qb, Kb, Vt, AO);

  gemm_proj<<<256, 256, 0, stream>>>(AO, wprojb, proj_b, out);
}